// Round 1
// baseline (718.344 us; speedup 1.0000x reference)
//
#include <hip/hip_runtime.h>
#include <math.h>

#define D 128

__device__ __forceinline__ float sigmoidf_(float x) { return 1.0f / (1.0f + expf(-x)); }

// ---- degree histogram over dst ----
__global__ void k_deg(const int* __restrict__ dst, int* __restrict__ cnt, int E) {
    int i = blockIdx.x * blockDim.x + threadIdx.x;
    if (i < E) atomicAdd(&cnt[dst[i]], 1);
}

// ---- dinv = rsqrt(deg + 1) ----
__global__ void k_dinv(const int* __restrict__ cnt, float* __restrict__ dinv, int N) {
    int i = blockIdx.x * blockDim.x + threadIdx.x;
    if (i < N) dinv[i] = rsqrtf((float)cnt[i] + 1.0f);
}

// ---- single-block exclusive scan of cnt -> row_ptr[0..N], row_ptr[N]=E ----
__global__ __launch_bounds__(1024) void k_scan(const int* __restrict__ cnt, int* __restrict__ row_ptr, int N) {
    __shared__ int partial[1024];
    int t = threadIdx.x;
    int per = (N + 1023) / 1024;
    int beg = t * per;
    int end = min(beg + per, N);
    int lsum = 0;
    for (int i = beg; i < end; ++i) lsum += cnt[i];
    partial[t] = lsum;
    __syncthreads();
    for (int off = 1; off < 1024; off <<= 1) {
        int v = (t >= off) ? partial[t - off] : 0;
        __syncthreads();
        partial[t] += v;
        __syncthreads();
    }
    int prefix = (t == 0) ? 0 : partial[t - 1];
    for (int i = beg; i < end; ++i) { row_ptr[i] = prefix; prefix += cnt[i]; }
    if (t == 0) row_ptr[N] = partial[1023];
}

// ---- counting-sort fill: CSR of incoming edges + per-edge norm ----
__global__ void k_fill(const int* __restrict__ src, const int* __restrict__ dst,
                       const float* __restrict__ dinv, const int* __restrict__ row_ptr,
                       int* __restrict__ fillc, int* __restrict__ s_sorted,
                       float* __restrict__ n_sorted, int E) {
    int i = blockIdx.x * blockDim.x + threadIdx.x;
    if (i >= E) return;
    int s = src[i], d = dst[i];
    int pos = row_ptr[d] + atomicAdd(&fillc[d], 1);
    s_sorted[pos] = s;
    n_sorted[pos] = dinv[s] * dinv[d];
}

// ---- FP32 GEMM: Y[M,128] = X[M,128] @ W[128,128] ----
__global__ __launch_bounds__(256) void k_gemm(const float* __restrict__ X, const float* __restrict__ W,
                                              float* __restrict__ Y, int M) {
    __shared__ float Xs[64][33];
    __shared__ float Ws[32][128];
    int block_row = blockIdx.x * 64;
    int tid = threadIdx.x;
    int tr = tid >> 4;   // 0..15
    int tc = tid & 15;   // 0..15
    float acc[4][8] = {};
    for (int k0 = 0; k0 < 128; k0 += 32) {
        for (int i = tid; i < 512; i += 256) {
            int r = i >> 3, kk = (i & 7) << 2;
            int row = block_row + r;
            float4 v = make_float4(0.f, 0.f, 0.f, 0.f);
            if (row < M) v = *(const float4*)&X[(size_t)row * D + k0 + kk];
            Xs[r][kk] = v.x; Xs[r][kk + 1] = v.y; Xs[r][kk + 2] = v.z; Xs[r][kk + 3] = v.w;
        }
        for (int i = tid; i < 1024; i += 256) {
            int r = i >> 5, cc = (i & 31) << 2;
            *(float4*)&Ws[r][cc] = *(const float4*)&W[(size_t)(k0 + r) * D + cc];
        }
        __syncthreads();
#pragma unroll
        for (int k = 0; k < 32; ++k) {
            float xv[4];
#pragma unroll
            for (int r = 0; r < 4; ++r) xv[r] = Xs[tr * 4 + r][k];
            float wv[8];
#pragma unroll
            for (int c = 0; c < 8; ++c) wv[c] = Ws[k][tc * 8 + c];
#pragma unroll
            for (int r = 0; r < 4; ++r)
#pragma unroll
                for (int c = 0; c < 8; ++c)
                    acc[r][c] += xv[r] * wv[c];
        }
        __syncthreads();
    }
    for (int r = 0; r < 4; ++r) {
        int row = block_row + tr * 4 + r;
        if (row < M) {
            float4* out = (float4*)&Y[(size_t)row * D + tc * 8];
            out[0] = make_float4(acc[r][0], acc[r][1], acc[r][2], acc[r][3]);
            out[1] = make_float4(acc[r][4], acc[r][5], acc[r][6], acc[r][7]);
        }
    }
}

// ---- CSR gather aggregation: out[n] = sum_e xw[src_e]*norm_e + xw[n]*dinv[n]^2 + b ----
template <bool RELU>
__global__ __launch_bounds__(128) void k_agg(const float* __restrict__ xw, const int* __restrict__ s_sorted,
                                             const float* __restrict__ n_sorted, const int* __restrict__ row_ptr,
                                             const float* __restrict__ dinv, const float* __restrict__ bias,
                                             float* __restrict__ out) {
    int n = blockIdx.x;
    int t = threadIdx.x;
    int beg = row_ptr[n], end = row_ptr[n + 1];
    float acc = 0.f;
    for (int e = beg; e < end; ++e) {
        int s = s_sorted[e];
        float w = n_sorted[e];
        acc += xw[(size_t)s * D + t] * w;
    }
    float di = dinv[n];
    acc += xw[(size_t)n * D + t] * di * di;
    acc += bias[t];
    if (RELU) acc = fmaxf(acc, 0.f);
    out[(size_t)n * D + t] = acc;
}

// ---- graph start offsets via binary search on sorted batch ----
__global__ void k_gstart(const int* __restrict__ batch, int* __restrict__ gstart, int N, int G) {
    int g = blockIdx.x * blockDim.x + threadIdx.x;
    if (g > G) return;
    int lo = 0, hi = N;
    while (lo < hi) {
        int mid = (lo + hi) >> 1;
        if (batch[mid] < g) lo = mid + 1; else hi = mid;
    }
    gstart[g] = lo;
}

// ---- LSTM step: one block per graph, 512 threads (one per gate element) ----
__global__ __launch_bounds__(512) void k_lstm(float* __restrict__ q_star, float* __restrict__ h,
                                              float* __restrict__ c, const float* __restrict__ Wih,
                                              const float* __restrict__ Whh, const float* __restrict__ bih,
                                              const float* __restrict__ bhh) {
    int g = blockIdx.x;
    int j = threadIdx.x;
    __shared__ float qs[2 * D];
    __shared__ float hs[D];
    __shared__ float gsh[4 * D];
    if (j < 2 * D) qs[j] = q_star[g * 2 * D + j];
    else if (j < 3 * D) hs[j - 2 * D] = h[g * D + (j - 2 * D)];
    __syncthreads();
    float acc = bih[j] + bhh[j];
    const float* wr = &Wih[(size_t)j * (2 * D)];
#pragma unroll 4
    for (int k = 0; k < 2 * D; ++k) acc += wr[k] * qs[k];
    const float* wh = &Whh[(size_t)j * D];
#pragma unroll 4
    for (int k = 0; k < D; ++k) acc += wh[k] * hs[k];
    gsh[j] = acc;
    __syncthreads();
    if (j < D) {
        float ig = gsh[j], fg = gsh[j + D], gg = gsh[j + 2 * D], og = gsh[j + 3 * D];
        float cc = sigmoidf_(fg) * c[g * D + j] + sigmoidf_(ig) * tanhf(gg);
        float hh = sigmoidf_(og) * tanhf(cc);
        c[g * D + j] = cc;
        h[g * D + j] = hh;
        q_star[g * 2 * D + j] = hh;  // q part of next q_star
    }
}

// ---- per-node attention logit: e[n] = dot(h2[n], q[batch[n]]) ----
__global__ __launch_bounds__(256) void k_e(const float* __restrict__ h2, const int* __restrict__ batch,
                                           const float* __restrict__ hq, float* __restrict__ e, int N) {
    int node = blockIdx.x * 4 + (threadIdx.x >> 6);
    if (node >= N) return;
    int lane = threadIdx.x & 63;
    int g = batch[node];
    const float2 xv = *(const float2*)&h2[(size_t)node * D + lane * 2];
    const float2 qv = *(const float2*)&hq[(size_t)g * D + lane * 2];
    float s = xv.x * qv.x + xv.y * qv.y;
#pragma unroll
    for (int off = 32; off; off >>= 1) s += __shfl_down(s, off);
    if (lane == 0) e[node] = s;
}

// ---- per-graph segment softmax + weighted sum -> r, written into q_star[g][D:2D] ----
__global__ __launch_bounds__(256) void k_attn(const float* __restrict__ h2, float* __restrict__ ebuf,
                                              const int* __restrict__ gstart, float* __restrict__ q_star) {
    int g = blockIdx.x;
    int s = gstart[g], epos = gstart[g + 1];
    int t = threadIdx.x;
    __shared__ float red[256];
    // phase 1: max
    float m = -1e30f;
    for (int i = s + t; i < epos; i += 256) m = fmaxf(m, ebuf[i]);
    red[t] = m;
    __syncthreads();
    for (int off = 128; off; off >>= 1) {
        if (t < off) red[t] = fmaxf(red[t], red[t + off]);
        __syncthreads();
    }
    m = red[0];
    if (!(m > -1e29f)) m = 0.f;  // empty-graph guard (matches ref isfinite guard)
    __syncthreads();
    // phase 2: exp + sum (in-place ex)
    float ssum = 0.f;
    for (int i = s + t; i < epos; i += 256) {
        float ex = expf(ebuf[i] - m);
        ebuf[i] = ex;
        ssum += ex;
    }
    red[t] = ssum;
    __syncthreads();
    for (int off = 128; off; off >>= 1) {
        if (t < off) red[t] += red[t + off];
        __syncthreads();
    }
    float inv = 1.0f / (red[0] + 1e-16f);
    __syncthreads();
    // phase 3: r[d] = inv * sum_i ex_i * h2[i][d]; split even/odd nodes across half-blocks
    int d = t & (D - 1);
    int half = t >> 7;
    float acc = 0.f;
    for (int i = s + half; i < epos; i += 2) acc += ebuf[i] * h2[(size_t)i * D + d];
    red[t] = acc;
    __syncthreads();
    if (t < D) {
        float r = (red[t] + red[t + D]) * inv;
        q_star[g * 2 * D + D + t] = r;
    }
}

extern "C" void kernel_launch(void* const* d_in, const int* in_sizes, int n_in,
                              void* d_out, int out_size, void* d_ws, size_t ws_size,
                              hipStream_t stream) {
    const float* x = (const float*)d_in[0];
    const int* ei = (const int*)d_in[1];
    const int* batch = (const int*)d_in[2];
    const float* W1 = (const float*)d_in[3];
    const float* b1 = (const float*)d_in[4];
    const float* W2 = (const float*)d_in[5];
    const float* b2 = (const float*)d_in[6];
    const float* Wih = (const float*)d_in[7];
    const float* Whh = (const float*)d_in[8];
    const float* bih = (const float*)d_in[9];
    const float* bhh = (const float*)d_in[10];

    int N = in_sizes[2];          // 50000 nodes
    int E = in_sizes[1] / 2;      // 625000 edges
    int G = out_size / (2 * D);   // 256 graphs
    const int* src = ei;
    const int* dst = ei + E;
    float* xbuf = (float*)d_in[0];  // reuse x's buffer for h1/h2 (inputs are restored before every timed launch)
    float* q_star = (float*)d_out;  // q_star lives in d_out

    float* wsf = (float*)d_ws;
    int* wsi = (int*)d_ws;
    size_t off = 0;
    float* dinv = wsf + off;   off += N;
    int* degcnt = wsi + off;   off += N;
    int* row_ptr = wsi + off;  off += N + 1; off = (off + 3) & ~(size_t)3;
    int* fillc = wsi + off;    off += N;
    int* s_sorted = wsi + off; off += E;
    float* n_sorted = wsf + off; off += E;
    off = (off + 3) & ~(size_t)3;
    float* bufA = wsf + off;   off += (size_t)N * D;  // xw buffer
    float* e_buf = wsf + off;  off += N;
    int* gstart = wsi + off;   off += G + 1; off = (off + 3) & ~(size_t)3;
    float* h_lstm = wsf + off; off += (size_t)G * D;
    float* c_lstm = wsf + off; off += (size_t)G * D;

    hipMemsetAsync(degcnt, 0, N * sizeof(int), stream);
    hipMemsetAsync(fillc, 0, N * sizeof(int), stream);
    hipMemsetAsync(h_lstm, 0, 2 * (size_t)G * D * sizeof(float), stream);  // h and c contiguous
    hipMemsetAsync(d_out, 0, (size_t)out_size * sizeof(float), stream);

    int eb = (E + 255) / 256;
    int nb = (N + 255) / 256;
    k_deg<<<eb, 256, 0, stream>>>(dst, degcnt, E);
    k_dinv<<<nb, 256, 0, stream>>>(degcnt, dinv, N);
    k_scan<<<1, 1024, 0, stream>>>(degcnt, row_ptr, N);
    k_fill<<<eb, 256, 0, stream>>>(src, dst, dinv, row_ptr, fillc, s_sorted, n_sorted, E);

    int gb = (N + 63) / 64;
    // conv1: xw1 = x @ W1 ; h1 = relu(agg + b1)  (h1 -> xbuf)
    k_gemm<<<gb, 256, 0, stream>>>(x, W1, bufA, N);
    k_agg<true><<<N, 128, 0, stream>>>(bufA, s_sorted, n_sorted, row_ptr, dinv, b1, xbuf);
    // conv2: xw2 = h1 @ W2 ; h2 = agg + b2  (h2 -> xbuf)
    k_gemm<<<gb, 256, 0, stream>>>(xbuf, W2, bufA, N);
    k_agg<false><<<N, 128, 0, stream>>>(bufA, s_sorted, n_sorted, row_ptr, dinv, b2, xbuf);

    k_gstart<<<(G + 256) / 256 + 1, 256, 0, stream>>>(batch, gstart, N, G);

    for (int step = 0; step < 3; ++step) {
        k_lstm<<<G, 512, 0, stream>>>(q_star, h_lstm, c_lstm, Wih, Whh, bih, bhh);
        k_e<<<(N + 3) / 4, 256, 0, stream>>>(xbuf, batch, h_lstm, e_buf, N);
        k_attn<<<G, 256, 0, stream>>>(xbuf, e_buf, gstart, q_star);
    }
}

// Round 2
// 526.936 us; speedup vs baseline: 1.3632x; 1.3632x over previous
//
#include <hip/hip_runtime.h>
#include <math.h>

#define D 128

__device__ __forceinline__ float sigmoidf_(float x) { return 1.0f / (1.0f + expf(-x)); }

// ---- degree histogram over dst ----
__global__ void k_deg(const int* __restrict__ dst, int* __restrict__ cnt, int E) {
    int i = blockIdx.x * blockDim.x + threadIdx.x;
    if (i < E) atomicAdd(&cnt[dst[i]], 1);
}

// ---- dinv = rsqrt(deg + 1) ----
__global__ void k_dinv(const int* __restrict__ cnt, float* __restrict__ dinv, int N) {
    int i = blockIdx.x * blockDim.x + threadIdx.x;
    if (i < N) dinv[i] = rsqrtf((float)cnt[i] + 1.0f);
}

// ---- 2-level scan: per-block exclusive scan + block sums ----
__global__ __launch_bounds__(256) void k_scan1(const int* __restrict__ cnt, int* __restrict__ row_ptr,
                                               int* __restrict__ bsum, int N) {
    __shared__ int sh[256];
    int t = threadIdx.x;
    int i = blockIdx.x * 256 + t;
    int v = (i < N) ? cnt[i] : 0;
    sh[t] = v;
    __syncthreads();
    for (int off = 1; off < 256; off <<= 1) {
        int u = (t >= off) ? sh[t - off] : 0;
        __syncthreads();
        sh[t] += u;
        __syncthreads();
    }
    if (i < N) row_ptr[i] = sh[t] - v;  // exclusive
    if (t == 255) bsum[blockIdx.x] = sh[255];
}

__global__ __launch_bounds__(256) void k_scan2(int* __restrict__ bsum, int nb) {
    __shared__ int sh[256];
    int t = threadIdx.x;
    int v = (t < nb) ? bsum[t] : 0;
    sh[t] = v;
    __syncthreads();
    for (int off = 1; off < 256; off <<= 1) {
        int u = (t >= off) ? sh[t - off] : 0;
        __syncthreads();
        sh[t] += u;
        __syncthreads();
    }
    if (t < nb) bsum[t] = sh[t] - v;  // exclusive
}

__global__ __launch_bounds__(256) void k_scan3(int* __restrict__ row_ptr, const int* __restrict__ bsum,
                                               int N, int E) {
    int i = blockIdx.x * 256 + threadIdx.x;
    if (i < N) row_ptr[i] += bsum[blockIdx.x];
    if (i == 0) row_ptr[N] = E;
}

// ---- counting-sort fill: CSR of incoming edges + per-edge norm ----
__global__ void k_fill(const int* __restrict__ src, const int* __restrict__ dst,
                       const float* __restrict__ dinv, const int* __restrict__ row_ptr,
                       int* __restrict__ fillc, int* __restrict__ s_sorted,
                       float* __restrict__ n_sorted, int E) {
    int i = blockIdx.x * blockDim.x + threadIdx.x;
    if (i >= E) return;
    int s = src[i], d = dst[i];
    int pos = row_ptr[d] + atomicAdd(&fillc[d], 1);
    s_sorted[pos] = s;
    n_sorted[pos] = dinv[s] * dinv[d];
}

// ---- FP32 GEMM: Y[M,128] = X[M,128] @ W[128,128], X^T-staged LDS ----
__global__ __launch_bounds__(256) void k_gemm(const float* __restrict__ X, const float* __restrict__ W,
                                              float* __restrict__ Y, int M) {
    __shared__ float Xs[32][68];   // Xs[k][row], row-dim padded: 68*4B=272B, 16B-aligned rows
    __shared__ float Ws[32][128];
    int block_row = blockIdx.x * 64;
    int tid = threadIdx.x;
    int trr = tid >> 4;   // 0..15 (row group)
    int tc = tid & 15;    // 0..15 (col group)
    float acc[4][8] = {};
    for (int k0 = 0; k0 < 128; k0 += 32) {
        for (int i = tid; i < 512; i += 256) {
            int r = i >> 3, kk = (i & 7) << 2;
            int row = block_row + r;
            float4 v = make_float4(0.f, 0.f, 0.f, 0.f);
            if (row < M) v = *(const float4*)&X[(size_t)row * D + k0 + kk];
            Xs[kk + 0][r] = v.x; Xs[kk + 1][r] = v.y; Xs[kk + 2][r] = v.z; Xs[kk + 3][r] = v.w;
        }
        for (int i = tid; i < 1024; i += 256) {
            int r = i >> 5, cc = (i & 31) << 2;
            *(float4*)&Ws[r][cc] = *(const float4*)&W[(size_t)(k0 + r) * D + cc];
        }
        __syncthreads();
#pragma unroll
        for (int k = 0; k < 32; ++k) {
            float4 xv = *(const float4*)&Xs[k][trr * 4];
            float4 w0 = *(const float4*)&Ws[k][tc * 4];
            float4 w1 = *(const float4*)&Ws[k][tc * 4 + 64];
            float xr[4] = {xv.x, xv.y, xv.z, xv.w};
            float wc[8] = {w0.x, w0.y, w0.z, w0.w, w1.x, w1.y, w1.z, w1.w};
#pragma unroll
            for (int r = 0; r < 4; ++r)
#pragma unroll
                for (int c = 0; c < 8; ++c)
                    acc[r][c] += xr[r] * wc[c];
        }
        __syncthreads();
    }
    for (int r = 0; r < 4; ++r) {
        int row = block_row + trr * 4 + r;
        if (row < M) {
            *(float4*)&Y[(size_t)row * D + tc * 4] = make_float4(acc[r][0], acc[r][1], acc[r][2], acc[r][3]);
            *(float4*)&Y[(size_t)row * D + 64 + tc * 4] = make_float4(acc[r][4], acc[r][5], acc[r][6], acc[r][7]);
        }
    }
}

// ---- CSR gather aggregation, wave-per-node, edge-unrolled x4 ----
// out[n] = sum_e xw[src_e]*norm_e + xw[n]*dinv[n]^2 + b  (+relu)
template <bool RELU>
__global__ __launch_bounds__(256) void k_agg(const float* __restrict__ xw, const int* __restrict__ s_sorted,
                                             const float* __restrict__ n_sorted, const int* __restrict__ row_ptr,
                                             const float* __restrict__ dinv, const float* __restrict__ bias,
                                             float* __restrict__ out, int N) {
    int n = blockIdx.x * 4 + (threadIdx.x >> 6);
    if (n >= N) return;
    int l = threadIdx.x & 63;
    int beg = row_ptr[n], end = row_ptr[n + 1];
    float2 a0 = {0.f, 0.f}, a1 = {0.f, 0.f}, a2 = {0.f, 0.f}, a3 = {0.f, 0.f};
    int e = beg;
    for (; e + 4 <= end; e += 4) {
        int s0 = s_sorted[e + 0], s1 = s_sorted[e + 1], s2 = s_sorted[e + 2], s3 = s_sorted[e + 3];
        float w0 = n_sorted[e + 0], w1 = n_sorted[e + 1], w2 = n_sorted[e + 2], w3 = n_sorted[e + 3];
        float2 x0 = *(const float2*)&xw[(size_t)s0 * D + 2 * l];
        float2 x1 = *(const float2*)&xw[(size_t)s1 * D + 2 * l];
        float2 x2 = *(const float2*)&xw[(size_t)s2 * D + 2 * l];
        float2 x3 = *(const float2*)&xw[(size_t)s3 * D + 2 * l];
        a0.x += x0.x * w0; a0.y += x0.y * w0;
        a1.x += x1.x * w1; a1.y += x1.y * w1;
        a2.x += x2.x * w2; a2.y += x2.y * w2;
        a3.x += x3.x * w3; a3.y += x3.y * w3;
    }
    for (; e < end; ++e) {
        int s = s_sorted[e];
        float w = n_sorted[e];
        float2 xv = *(const float2*)&xw[(size_t)s * D + 2 * l];
        a0.x += xv.x * w; a0.y += xv.y * w;
    }
    float di = dinv[n];
    float dw = di * di;
    float2 xs = *(const float2*)&xw[(size_t)n * D + 2 * l];
    float rx = a0.x + a1.x + a2.x + a3.x + xs.x * dw + bias[2 * l];
    float ry = a0.y + a1.y + a2.y + a3.y + xs.y * dw + bias[2 * l + 1];
    if (RELU) { rx = fmaxf(rx, 0.f); ry = fmaxf(ry, 0.f); }
    *(float2*)&out[(size_t)n * D + 2 * l] = make_float2(rx, ry);
}

// ---- graph start offsets via binary search on sorted batch ----
__global__ void k_gstart(const int* __restrict__ batch, int* __restrict__ gstart, int N, int G) {
    int g = blockIdx.x * blockDim.x + threadIdx.x;
    if (g > G) return;
    int lo = 0, hi = N;
    while (lo < hi) {
        int mid = (lo + hi) >> 1;
        if (batch[mid] < g) lo = mid + 1; else hi = mid;
    }
    gstart[g] = lo;
}

// ---- tiled transpose W[R][C] -> WT[C][R] ----
__global__ __launch_bounds__(256) void k_transpose(const float* __restrict__ W, float* __restrict__ WT,
                                                   int R, int C) {
    __shared__ float tile[32][33];
    int tx = threadIdx.x & 31, ty = threadIdx.x >> 5;  // ty 0..7
    int nbc = C >> 5;
    int c0 = (blockIdx.x % nbc) << 5;
    int r0 = (blockIdx.x / nbc) << 5;
#pragma unroll
    for (int i = 0; i < 32; i += 8) tile[ty + i][tx] = W[(size_t)(r0 + ty + i) * C + c0 + tx];
    __syncthreads();
#pragma unroll
    for (int i = 0; i < 32; i += 8) WT[(size_t)(c0 + ty + i) * R + r0 + tx] = tile[tx][ty + i];
}

// ---- LSTM step with transposed (coalesced) weights ----
__global__ __launch_bounds__(512) void k_lstm(float* __restrict__ q_star, float* __restrict__ h,
                                              float* __restrict__ c, const float* __restrict__ WihT,
                                              const float* __restrict__ WhhT, const float* __restrict__ bih,
                                              const float* __restrict__ bhh) {
    int g = blockIdx.x;
    int j = threadIdx.x;  // 0..511, one gate element each
    __shared__ float qs[2 * D];
    __shared__ float hs[D];
    __shared__ float gsh[4 * D];
    if (j < 2 * D) qs[j] = q_star[g * 2 * D + j];
    else if (j < 3 * D) hs[j - 2 * D] = h[g * D + (j - 2 * D)];
    __syncthreads();
    float acc = bih[j] + bhh[j];
#pragma unroll 8
    for (int k = 0; k < 2 * D; ++k) acc += qs[k] * WihT[(size_t)k * (4 * D) + j];  // coalesced across j
#pragma unroll 8
    for (int k = 0; k < D; ++k) acc += hs[k] * WhhT[(size_t)k * (4 * D) + j];
    gsh[j] = acc;
    __syncthreads();
    if (j < D) {
        float ig = gsh[j], fg = gsh[j + D], gg = gsh[j + 2 * D], og = gsh[j + 3 * D];
        float cc = sigmoidf_(fg) * c[g * D + j] + sigmoidf_(ig) * tanhf(gg);
        float hh = sigmoidf_(og) * tanhf(cc);
        c[g * D + j] = cc;
        h[g * D + j] = hh;
        q_star[g * 2 * D + j] = hh;
    }
}

// ---- fused attention: e = h2 . q[batch], segment softmax, r = sum a_i h2_i ----
__global__ __launch_bounds__(256) void k_attn(const float* __restrict__ h2, const float* __restrict__ hq,
                                              float* __restrict__ ebuf, const int* __restrict__ gstart,
                                              float* __restrict__ q_star) {
    int g = blockIdx.x;
    int s = gstart[g], epos = gstart[g + 1];
    int t = threadIdx.x;
    int wid = t >> 6, l = t & 63;
    __shared__ float red[256];
    __shared__ float2 racc2[256];
    float2 qv = *(const float2*)&hq[(size_t)g * D + 2 * l];
    // phase 1: e[i] = dot(h2[i], q); wave-per-node; track max
    float m = -1e30f;
    for (int i = s + wid; i < epos; i += 4) {
        float2 xv = *(const float2*)&h2[(size_t)i * D + 2 * l];
        float d = xv.x * qv.x + xv.y * qv.y;
#pragma unroll
        for (int off = 32; off; off >>= 1) d += __shfl_down(d, off);
        d = __shfl(d, 0);
        if (l == 0) ebuf[i] = d;
        m = fmaxf(m, d);
    }
    red[t] = m;
    __syncthreads();
    for (int off = 128; off; off >>= 1) {
        if (t < off) red[t] = fmaxf(red[t], red[t + off]);
        __syncthreads();
    }
    m = red[0];
    if (!(m > -1e29f)) m = 0.f;  // empty-graph guard
    __syncthreads();
    // phase 2: exp + sum (in-place on ebuf)
    float ssum = 0.f;
    for (int i = s + t; i < epos; i += 256) {
        float ex = expf(ebuf[i] - m);
        ebuf[i] = ex;
        ssum += ex;
    }
    red[t] = ssum;
    __syncthreads();
    for (int off = 128; off; off >>= 1) {
        if (t < off) red[t] += red[t + off];
        __syncthreads();
    }
    float inv = 1.0f / (red[0] + 1e-16f);
    __syncthreads();
    // phase 3: r = sum_i ex_i * h2[i]; wave-per-node, float2 per lane
    float2 acc = {0.f, 0.f};
    for (int i = s + wid; i < epos; i += 4) {
        float w = ebuf[i];
        float2 xv = *(const float2*)&h2[(size_t)i * D + 2 * l];
        acc.x += xv.x * w;
        acc.y += xv.y * w;
    }
    racc2[t] = acc;
    __syncthreads();
    if (t < 64) {
        float2 r0 = racc2[t], r1 = racc2[64 + t], r2 = racc2[128 + t], r3 = racc2[192 + t];
        float2 r = make_float2((r0.x + r1.x + r2.x + r3.x) * inv, (r0.y + r1.y + r2.y + r3.y) * inv);
        *(float2*)&q_star[g * 2 * D + D + 2 * t] = r;
    }
}

extern "C" void kernel_launch(void* const* d_in, const int* in_sizes, int n_in,
                              void* d_out, int out_size, void* d_ws, size_t ws_size,
                              hipStream_t stream) {
    const float* x = (const float*)d_in[0];
    const int* ei = (const int*)d_in[1];
    const int* batch = (const int*)d_in[2];
    const float* W1 = (const float*)d_in[3];
    const float* b1 = (const float*)d_in[4];
    const float* W2 = (const float*)d_in[5];
    const float* b2 = (const float*)d_in[6];
    const float* Wih = (const float*)d_in[7];
    const float* Whh = (const float*)d_in[8];
    const float* bih = (const float*)d_in[9];
    const float* bhh = (const float*)d_in[10];

    int N = in_sizes[2];          // 50000
    int E = in_sizes[1] / 2;      // 625000
    int G = out_size / (2 * D);   // 256
    const int* src = ei;
    const int* dst = ei + E;
    float* xbuf = (float*)d_in[0];  // reuse x's buffer for h1/h2 (inputs restored before every call)
    float* q_star = (float*)d_out;

    float* wsf = (float*)d_ws;
    int* wsi = (int*)d_ws;
    size_t off = 0;
    float* dinv = wsf + off;    off += N;
    int* degcnt = wsi + off;    off += N;
    int* row_ptr = wsi + off;   off += N + 1;
    int* bsum = wsi + off;      off += 256;
    off = (off + 3) & ~(size_t)3;
    int* fillc = wsi + off;     off += N;
    int* s_sorted = wsi + off;  off += E;
    float* n_sorted = wsf + off; off += E;
    off = (off + 3) & ~(size_t)3;
    float* bufA = wsf + off;    off += (size_t)N * D;
    float* e_buf = wsf + off;   off += N;
    int* gstart = wsi + off;    off += G + 1;
    off = (off + 3) & ~(size_t)3;
    float* h_lstm = wsf + off;  off += (size_t)G * D;
    float* c_lstm = wsf + off;  off += (size_t)G * D;
    float* WihT = wsf + off;    off += 256 * 512;
    float* WhhT = wsf + off;    off += 128 * 512;

    hipMemsetAsync(degcnt, 0, N * sizeof(int), stream);
    hipMemsetAsync(fillc, 0, N * sizeof(int), stream);
    hipMemsetAsync(h_lstm, 0, 2 * (size_t)G * D * sizeof(float), stream);  // h and c contiguous
    hipMemsetAsync(d_out, 0, (size_t)out_size * sizeof(float), stream);

    int eb = (E + 255) / 256;
    int nb = (N + 255) / 256;   // 196
    k_deg<<<eb, 256, 0, stream>>>(dst, degcnt, E);
    k_dinv<<<nb, 256, 0, stream>>>(degcnt, dinv, N);
    k_scan1<<<nb, 256, 0, stream>>>(degcnt, row_ptr, bsum, N);
    k_scan2<<<1, 256, 0, stream>>>(bsum, nb);
    k_scan3<<<nb, 256, 0, stream>>>(row_ptr, bsum, N, E);
    k_fill<<<eb, 256, 0, stream>>>(src, dst, dinv, row_ptr, fillc, s_sorted, n_sorted, E);

    k_transpose<<<(256 / 32) * (512 / 32), 256, 0, stream>>>(Wih, WihT, 512, 256);
    k_transpose<<<(128 / 32) * (512 / 32), 256, 0, stream>>>(Whh, WhhT, 512, 128);

    int gb = (N + 63) / 64;
    k_gemm<<<gb, 256, 0, stream>>>(x, W1, bufA, N);
    k_agg<true><<<(N + 3) / 4, 256, 0, stream>>>(bufA, s_sorted, n_sorted, row_ptr, dinv, b1, xbuf, N);
    k_gemm<<<gb, 256, 0, stream>>>(xbuf, W2, bufA, N);
    k_agg<false><<<(N + 3) / 4, 256, 0, stream>>>(bufA, s_sorted, n_sorted, row_ptr, dinv, b2, xbuf, N);

    k_gstart<<<(G + 256) / 256, 256, 0, stream>>>(batch, gstart, N, G);

    for (int step = 0; step < 3; ++step) {
        k_lstm<<<G, 512, 0, stream>>>(q_star, h_lstm, c_lstm, WihT, WhhT, bih, bhh);
        k_attn<<<G, 256, 0, stream>>>(xbuf, h_lstm, e_buf, gstart, q_star);
    }
}

// Round 3
// 429.017 us; speedup vs baseline: 1.6744x; 1.2282x over previous
//
#include <hip/hip_runtime.h>
#include <math.h>

#define D 128

__device__ __forceinline__ float sigmoidf_(float x) { return 1.0f / (1.0f + expf(-x)); }

// ---- degree histogram over dst ----
__global__ void k_deg(const int* __restrict__ dst, int* __restrict__ cnt, int E) {
    int i = blockIdx.x * blockDim.x + threadIdx.x;
    if (i < E) atomicAdd(&cnt[dst[i]], 1);
}

// ---- dinv = rsqrt(deg + 1) ----
__global__ void k_dinv(const int* __restrict__ cnt, float* __restrict__ dinv, int N) {
    int i = blockIdx.x * blockDim.x + threadIdx.x;
    if (i < N) dinv[i] = rsqrtf((float)cnt[i] + 1.0f);
}

// ---- 2-level scan ----
__global__ __launch_bounds__(256) void k_scan1(const int* __restrict__ cnt, int* __restrict__ row_ptr,
                                               int* __restrict__ bsum, int N) {
    __shared__ int sh[256];
    int t = threadIdx.x;
    int i = blockIdx.x * 256 + t;
    int v = (i < N) ? cnt[i] : 0;
    sh[t] = v;
    __syncthreads();
    for (int off = 1; off < 256; off <<= 1) {
        int u = (t >= off) ? sh[t - off] : 0;
        __syncthreads();
        sh[t] += u;
        __syncthreads();
    }
    if (i < N) row_ptr[i] = sh[t] - v;
    if (t == 255) bsum[blockIdx.x] = sh[255];
}

__global__ __launch_bounds__(256) void k_scan2(int* __restrict__ bsum, int nb) {
    __shared__ int sh[256];
    int t = threadIdx.x;
    int v = (t < nb) ? bsum[t] : 0;
    sh[t] = v;
    __syncthreads();
    for (int off = 1; off < 256; off <<= 1) {
        int u = (t >= off) ? sh[t - off] : 0;
        __syncthreads();
        sh[t] += u;
        __syncthreads();
    }
    if (t < nb) bsum[t] = sh[t] - v;
}

__global__ __launch_bounds__(256) void k_scan3(int* __restrict__ row_ptr, const int* __restrict__ bsum,
                                               int N, int E) {
    int i = blockIdx.x * 256 + threadIdx.x;
    if (i < N) row_ptr[i] += bsum[blockIdx.x];
    if (i == 0) row_ptr[N] = E;
}

// ---- counting-sort fill: CSR of incoming edges + per-edge norm ----
__global__ void k_fill(const int* __restrict__ src, const int* __restrict__ dst,
                       const float* __restrict__ dinv, const int* __restrict__ row_ptr,
                       int* __restrict__ fillc, int* __restrict__ s_sorted,
                       float* __restrict__ n_sorted, int E) {
    int i = blockIdx.x * blockDim.x + threadIdx.x;
    if (i >= E) return;
    int s = src[i], d = dst[i];
    int pos = row_ptr[d] + atomicAdd(&fillc[d], 1);
    s_sorted[pos] = s;
    n_sorted[pos] = dinv[s] * dinv[d];
}

// ---- FP32 GEMM: Y[M,128] = X[M,128] @ W[128,128], X^T-staged LDS ----
__global__ __launch_bounds__(256) void k_gemm(const float* __restrict__ X, const float* __restrict__ W,
                                              float* __restrict__ Y, int M) {
    __shared__ float Xs[32][68];
    __shared__ float Ws[32][128];
    int block_row = blockIdx.x * 64;
    int tid = threadIdx.x;
    int trr = tid >> 4;
    int tc = tid & 15;
    float acc[4][8] = {};
    for (int k0 = 0; k0 < 128; k0 += 32) {
        for (int i = tid; i < 512; i += 256) {
            int r = i >> 3, kk = (i & 7) << 2;
            int row = block_row + r;
            float4 v = make_float4(0.f, 0.f, 0.f, 0.f);
            if (row < M) v = *(const float4*)&X[(size_t)row * D + k0 + kk];
            Xs[kk + 0][r] = v.x; Xs[kk + 1][r] = v.y; Xs[kk + 2][r] = v.z; Xs[kk + 3][r] = v.w;
        }
        for (int i = tid; i < 1024; i += 256) {
            int r = i >> 5, cc = (i & 31) << 2;
            *(float4*)&Ws[r][cc] = *(const float4*)&W[(size_t)(k0 + r) * D + cc];
        }
        __syncthreads();
#pragma unroll
        for (int k = 0; k < 32; ++k) {
            float4 xv = *(const float4*)&Xs[k][trr * 4];
            float4 w0 = *(const float4*)&Ws[k][tc * 4];
            float4 w1 = *(const float4*)&Ws[k][tc * 4 + 64];
            float xr[4] = {xv.x, xv.y, xv.z, xv.w};
            float wc[8] = {w0.x, w0.y, w0.z, w0.w, w1.x, w1.y, w1.z, w1.w};
#pragma unroll
            for (int r = 0; r < 4; ++r)
#pragma unroll
                for (int c = 0; c < 8; ++c)
                    acc[r][c] += xr[r] * wc[c];
        }
        __syncthreads();
    }
    for (int r = 0; r < 4; ++r) {
        int row = block_row + trr * 4 + r;
        if (row < M) {
            *(float4*)&Y[(size_t)row * D + tc * 4] = make_float4(acc[r][0], acc[r][1], acc[r][2], acc[r][3]);
            *(float4*)&Y[(size_t)row * D + 64 + tc * 4] = make_float4(acc[r][4], acc[r][5], acc[r][6], acc[r][7]);
        }
    }
}

// ---- CSR gather aggregation, wave-per-node, 8 rows in flight, branchless tail ----
template <bool RELU>
__global__ __launch_bounds__(256) void k_agg(const float* __restrict__ xw, const int* __restrict__ s_sorted,
                                             const float* __restrict__ n_sorted, const int* __restrict__ row_ptr,
                                             const float* __restrict__ dinv, const float* __restrict__ bias,
                                             float* __restrict__ out, int N) {
    int n = blockIdx.x * 4 + (threadIdx.x >> 6);
    if (n >= N) return;
    int l = threadIdx.x & 63;
    int beg = row_ptr[n], end = row_ptr[n + 1];
    float2 a[8];
#pragma unroll
    for (int k = 0; k < 8; ++k) a[k] = make_float2(0.f, 0.f);
    for (int e = beg; e < end; e += 8) {
#pragma unroll
        for (int k = 0; k < 8; ++k) {
            int ee = min(e + k, end - 1);           // clamp: always a valid address
            int s = s_sorted[ee];
            float wgt = n_sorted[ee];
            wgt = (e + k < end) ? wgt : 0.f;        // mask dummy edges to 0
            float2 xv = *(const float2*)&xw[(size_t)s * D + 2 * l];
            a[k].x += xv.x * wgt;
            a[k].y += xv.y * wgt;
        }
    }
    float di = dinv[n];
    float dw = di * di;
    float2 xs = *(const float2*)&xw[(size_t)n * D + 2 * l];
    float2 bv = *(const float2*)&bias[2 * l];
    float rx = ((a[0].x + a[1].x) + (a[2].x + a[3].x)) + ((a[4].x + a[5].x) + (a[6].x + a[7].x))
               + xs.x * dw + bv.x;
    float ry = ((a[0].y + a[1].y) + (a[2].y + a[3].y)) + ((a[4].y + a[5].y) + (a[6].y + a[7].y))
               + xs.y * dw + bv.y;
    if (RELU) { rx = fmaxf(rx, 0.f); ry = fmaxf(ry, 0.f); }
    *(float2*)&out[(size_t)n * D + 2 * l] = make_float2(rx, ry);
}

// ---- graph start offsets via binary search on sorted batch ----
__global__ void k_gstart(const int* __restrict__ batch, int* __restrict__ gstart, int N, int G) {
    int g = blockIdx.x * blockDim.x + threadIdx.x;
    if (g > G) return;
    int lo = 0, hi = N;
    while (lo < hi) {
        int mid = (lo + hi) >> 1;
        if (batch[mid] < g) lo = mid + 1; else hi = mid;
    }
    gstart[g] = lo;
}

// ---- tiled transpose W[R][C] -> WT[C][R] ----
__global__ __launch_bounds__(256) void k_transpose(const float* __restrict__ W, float* __restrict__ WT,
                                                   int R, int C) {
    __shared__ float tile[32][33];
    int tx = threadIdx.x & 31, ty = threadIdx.x >> 5;
    int nbc = C >> 5;
    int c0 = (blockIdx.x % nbc) << 5;
    int r0 = (blockIdx.x / nbc) << 5;
#pragma unroll
    for (int i = 0; i < 32; i += 8) tile[ty + i][tx] = W[(size_t)(r0 + ty + i) * C + c0 + tx];
    __syncthreads();
#pragma unroll
    for (int i = 0; i < 32; i += 8) WT[(size_t)(c0 + ty + i) * R + r0 + tx] = tile[tx][ty + i];
}

// ---- fully fused Set2Set: 3 steps of {LSTM, segment-softmax attention} per graph ----
// one block per graph, 512 threads (8 waves); h/c/q_star live in LDS across steps
__global__ __launch_bounds__(512) void k_set2set(const float* __restrict__ h2, const int* __restrict__ gstart,
                                                 const float* __restrict__ WihT, const float* __restrict__ WhhT,
                                                 const float* __restrict__ bih, const float* __restrict__ bhh,
                                                 float* __restrict__ ebuf, float* __restrict__ q_star) {
    int g = blockIdx.x;
    int t = threadIdx.x;           // 0..511
    int wid = t >> 6, l = t & 63;
    int s = gstart[g], epos = gstart[g + 1];
    __shared__ float qs[2 * D];    // local q_star = [q, r]
    __shared__ float hs[D], cs[D];
    __shared__ float gsh[4 * D];
    __shared__ float red[512];
    __shared__ float2 racc2[512];
    if (t < 2 * D) qs[t] = 0.f;
    if (t < D) { hs[t] = 0.f; cs[t] = 0.f; }
    float bsum_j = bih[t] + bhh[t];
    __syncthreads();
    for (int step = 0; step < 3; ++step) {
        // ---- LSTM gates: thread t computes gate element t (coalesced WT reads) ----
        float acc0 = bsum_j, acc1 = 0.f;
#pragma unroll 8
        for (int k = 0; k < 2 * D; k += 2) {
            acc0 += qs[k] * WihT[(size_t)k * (4 * D) + t];
            acc1 += qs[k + 1] * WihT[(size_t)(k + 1) * (4 * D) + t];
        }
#pragma unroll 8
        for (int k = 0; k < D; k += 2) {
            acc0 += hs[k] * WhhT[(size_t)k * (4 * D) + t];
            acc1 += hs[k + 1] * WhhT[(size_t)(k + 1) * (4 * D) + t];
        }
        gsh[t] = acc0 + acc1;
        __syncthreads();
        if (t < D) {
            float ig = gsh[t], fg = gsh[t + D], gg = gsh[t + 2 * D], og = gsh[t + 3 * D];
            float cc = sigmoidf_(fg) * cs[t] + sigmoidf_(ig) * tanhf(gg);
            float hh = sigmoidf_(og) * tanhf(cc);
            cs[t] = cc; hs[t] = hh; qs[t] = hh;
        }
        __syncthreads();
        // ---- attention phase 1: e[i] = h2[i].q, wave-per-node, track max ----
        float2 qv = *(const float2*)&hs[2 * l];
        float m = -1e30f;
        for (int i = s + wid; i < epos; i += 8) {
            float2 xv = *(const float2*)&h2[(size_t)i * D + 2 * l];
            float d = xv.x * qv.x + xv.y * qv.y;
#pragma unroll
            for (int off = 32; off; off >>= 1) d += __shfl_down(d, off);
            d = __shfl(d, 0);
            if (l == 0) ebuf[i] = d;
            m = fmaxf(m, d);
        }
        red[t] = m;
        __syncthreads();
        for (int off = 256; off; off >>= 1) {
            if (t < off) red[t] = fmaxf(red[t], red[t + off]);
            __syncthreads();
        }
        m = red[0];
        if (!(m > -1e29f)) m = 0.f;   // empty-graph guard
        __syncthreads();
        // ---- phase 2: exp + sum ----
        float ssum = 0.f;
        for (int i = s + t; i < epos; i += 512) {
            float ex = expf(ebuf[i] - m);
            ebuf[i] = ex;
            ssum += ex;
        }
        red[t] = ssum;
        __syncthreads();
        for (int off = 256; off; off >>= 1) {
            if (t < off) red[t] += red[t + off];
            __syncthreads();
        }
        float inv = 1.0f / (red[0] + 1e-16f);
        __syncthreads();
        // ---- phase 3: r = sum_i ex_i * h2[i] ----
        float2 racc = make_float2(0.f, 0.f);
        for (int i = s + wid; i < epos; i += 8) {
            float w = ebuf[i];
            float2 xv = *(const float2*)&h2[(size_t)i * D + 2 * l];
            racc.x += xv.x * w;
            racc.y += xv.y * w;
        }
        racc2[t] = racc;
        __syncthreads();
        if (t < 64) {
            float2 r = make_float2(0.f, 0.f);
#pragma unroll
            for (int w = 0; w < 8; ++w) { r.x += racc2[t + 64 * w].x; r.y += racc2[t + 64 * w].y; }
            qs[D + 2 * t] = r.x * inv;
            qs[D + 2 * t + 1] = r.y * inv;
        }
        __syncthreads();
    }
    if (t < 2 * D) q_star[g * 2 * D + t] = qs[t];
}

extern "C" void kernel_launch(void* const* d_in, const int* in_sizes, int n_in,
                              void* d_out, int out_size, void* d_ws, size_t ws_size,
                              hipStream_t stream) {
    const float* x = (const float*)d_in[0];
    const int* ei = (const int*)d_in[1];
    const int* batch = (const int*)d_in[2];
    const float* W1 = (const float*)d_in[3];
    const float* b1 = (const float*)d_in[4];
    const float* W2 = (const float*)d_in[5];
    const float* b2 = (const float*)d_in[6];
    const float* Wih = (const float*)d_in[7];
    const float* Whh = (const float*)d_in[8];
    const float* bih = (const float*)d_in[9];
    const float* bhh = (const float*)d_in[10];

    int N = in_sizes[2];          // 50000
    int E = in_sizes[1] / 2;      // 625000
    int G = out_size / (2 * D);   // 256
    const int* src = ei;
    const int* dst = ei + E;
    float* xbuf = (float*)d_in[0];  // reuse x's buffer for h1/h2 (inputs restored before every call)
    float* q_star = (float*)d_out;

    float* wsf = (float*)d_ws;
    int* wsi = (int*)d_ws;
    size_t off = 0;
    float* dinv = wsf + off;    off += N;
    int* degcnt = wsi + off;    off += N;
    int* row_ptr = wsi + off;   off += N + 1;
    int* bsum = wsi + off;      off += 256;
    off = (off + 3) & ~(size_t)3;
    int* fillc = wsi + off;     off += N;
    int* s_sorted = wsi + off;  off += E;
    float* n_sorted = wsf + off; off += E;
    off = (off + 3) & ~(size_t)3;
    float* bufA = wsf + off;    off += (size_t)N * D;
    float* e_buf = wsf + off;   off += N;
    int* gstart = wsi + off;    off += G + 1;
    off = (off + 3) & ~(size_t)3;
    float* WihT = wsf + off;    off += 256 * 512;
    float* WhhT = wsf + off;    off += 128 * 512;

    hipMemsetAsync(degcnt, 0, N * sizeof(int), stream);
    hipMemsetAsync(fillc, 0, N * sizeof(int), stream);

    int eb = (E + 255) / 256;
    int nb = (N + 255) / 256;
    k_deg<<<eb, 256, 0, stream>>>(dst, degcnt, E);
    k_dinv<<<nb, 256, 0, stream>>>(degcnt, dinv, N);
    k_scan1<<<nb, 256, 0, stream>>>(degcnt, row_ptr, bsum, N);
    k_scan2<<<1, 256, 0, stream>>>(bsum, nb);
    k_scan3<<<nb, 256, 0, stream>>>(row_ptr, bsum, N, E);
    k_fill<<<eb, 256, 0, stream>>>(src, dst, dinv, row_ptr, fillc, s_sorted, n_sorted, E);

    k_transpose<<<(256 / 32) * (512 / 32), 256, 0, stream>>>(Wih, WihT, 512, 256);
    k_transpose<<<(128 / 32) * (512 / 32), 256, 0, stream>>>(Whh, WhhT, 512, 128);
    k_gstart<<<(G + 256) / 256, 256, 0, stream>>>(batch, gstart, N, G);

    int gb = (N + 63) / 64;
    k_gemm<<<gb, 256, 0, stream>>>(x, W1, bufA, N);
    k_agg<true><<<(N + 3) / 4, 256, 0, stream>>>(bufA, s_sorted, n_sorted, row_ptr, dinv, b1, xbuf, N);
    k_gemm<<<gb, 256, 0, stream>>>(xbuf, W2, bufA, N);
    k_agg<false><<<(N + 3) / 4, 256, 0, stream>>>(bufA, s_sorted, n_sorted, row_ptr, dinv, b2, xbuf, N);

    k_set2set<<<G, 512, 0, stream>>>(xbuf, gstart, WihT, WhhT, bih, bhh, e_buf, q_star);
}